// Round 1
// baseline (51.267 us; speedup 1.0000x reference)
//
#include <hip/hip_runtime.h>

#define DIM 1024
#define RPW 4        // rows per wave
#define WAVES 4      // waves per block
#define ROWS_PER_BLOCK (RPW * WAVES)

// Butterfly mixer: 10 stages, stage i mixes (j, j+2^i) with Ws[i][p], p = j with bit i removed.
// Element j = q*256 + lane*4 + c  (q,c in [0,4), lane in [0,64)) lives in d[r][q*4+c].
// -> bits {0,1} = c, bits {2..7} = lane, bits {8,9} = q.
// Stages 0,1,8,9 are thread-local; stages 2..7 are __shfl_xor with mask 2^(i-2).
__global__ __launch_bounds__(256) void butterfly_kernel(
    const float* __restrict__ x,
    const float* __restrict__ Ws,
    float* __restrict__ out,
    int rows)
{
    const int lane = threadIdx.x & 63;
    const int wave = threadIdx.x >> 6;
    const int row0 = (blockIdx.x * WAVES + wave) * RPW;

    const float4* __restrict__ Wm = (const float4*)Ws;  // Wm[i*512 + p] = 2x2 matrix (W00,W01,W10,W11)

    float d[RPW][16];

    // ---- load: coalesced float4 ----
    #pragma unroll
    for (int r = 0; r < RPW; ++r) {
        int row = row0 + r;
        if (row < rows) {
            const float4* src = (const float4*)(x + (size_t)row * DIM);
            #pragma unroll
            for (int q = 0; q < 4; ++q) {
                float4 v = src[q * 64 + lane];
                d[r][q*4+0] = v.x; d[r][q*4+1] = v.y;
                d[r][q*4+2] = v.z; d[r][q*4+3] = v.w;
            }
        } else {
            #pragma unroll
            for (int e = 0; e < 16; ++e) d[r][e] = 0.f;
        }
    }

    // ---- stage 0: pairs (c,c+1); p = q*128 + lane*2 + (c>>1) ----
    #pragma unroll
    for (int q = 0; q < 4; ++q) {
        int base = 0*512 + q*128 + lane*2;
        float4 m0 = Wm[base], m1 = Wm[base+1];
        #pragma unroll
        for (int r = 0; r < RPW; ++r) {
            int e = q*4;
            float u = d[r][e+0], v = d[r][e+1];
            d[r][e+0] = u*m0.x + v*m0.z;
            d[r][e+1] = u*m0.y + v*m0.w;
            u = d[r][e+2]; v = d[r][e+3];
            d[r][e+2] = u*m1.x + v*m1.z;
            d[r][e+3] = u*m1.y + v*m1.w;
        }
    }

    // ---- stage 1: pairs (c,c+2); p = q*128 + lane*2 + (c&1) ----
    #pragma unroll
    for (int q = 0; q < 4; ++q) {
        int base = 1*512 + q*128 + lane*2;
        float4 m0 = Wm[base], m1 = Wm[base+1];
        #pragma unroll
        for (int r = 0; r < RPW; ++r) {
            int e = q*4;
            float u = d[r][e+0], v = d[r][e+2];
            d[r][e+0] = u*m0.x + v*m0.z;
            d[r][e+2] = u*m0.y + v*m0.w;
            u = d[r][e+1]; v = d[r][e+3];
            d[r][e+1] = u*m1.x + v*m1.z;
            d[r][e+3] = u*m1.y + v*m1.w;
        }
    }

    // ---- stages 2..7: cross-lane, mask m = 2^(i-2), a = bit (i-2) of lane ----
    // p = ((q*64+lane)>>(i-1))<<i | (lane & (m-1))*4 + c   (4 consecutive p per q)
    // new = mine*W[a][a] + other*W[a^1][a]
    #pragma unroll
    for (int i = 2; i < 8; ++i) {
        const int m = 1 << (i - 2);
        const int a = (lane >> (i - 2)) & 1;
        #pragma unroll
        for (int q = 0; q < 4; ++q) {
            int P0 = (((q*64 + lane) >> (i-1)) << i) | ((lane & (m-1)) << 2);
            int base = i*512 + P0;
            float4 M0 = Wm[base+0], M1 = Wm[base+1], M2 = Wm[base+2], M3 = Wm[base+3];
            // per-lane column select, hoisted out of the row loop
            float wA0 = a ? M0.w : M0.x, wB0 = a ? M0.y : M0.z;
            float wA1 = a ? M1.w : M1.x, wB1 = a ? M1.y : M1.z;
            float wA2 = a ? M2.w : M2.x, wB2 = a ? M2.y : M2.z;
            float wA3 = a ? M3.w : M3.x, wB3 = a ? M3.y : M3.z;
            #pragma unroll
            for (int r = 0; r < RPW; ++r) {
                int e = q*4;
                float o0 = __shfl_xor(d[r][e+0], m);
                float o1 = __shfl_xor(d[r][e+1], m);
                float o2 = __shfl_xor(d[r][e+2], m);
                float o3 = __shfl_xor(d[r][e+3], m);
                d[r][e+0] = d[r][e+0]*wA0 + o0*wB0;
                d[r][e+1] = d[r][e+1]*wA1 + o1*wB1;
                d[r][e+2] = d[r][e+2]*wA2 + o2*wB2;
                d[r][e+3] = d[r][e+3]*wA3 + o3*wB3;
            }
        }
    }

    // ---- stage 8: pairs (q, q+1) for q in {0,2}; p = (q>>1)*256 + lane*4 + c ----
    #pragma unroll
    for (int qp = 0; qp < 2; ++qp) {
        int base = 8*512 + qp*256 + lane*4;
        float4 M0 = Wm[base+0], M1 = Wm[base+1], M2 = Wm[base+2], M3 = Wm[base+3];
        #pragma unroll
        for (int r = 0; r < RPW; ++r) {
            int eu = (2*qp)*4, ev = (2*qp+1)*4;
            float u, v;
            u = d[r][eu+0]; v = d[r][ev+0]; d[r][eu+0] = u*M0.x + v*M0.z; d[r][ev+0] = u*M0.y + v*M0.w;
            u = d[r][eu+1]; v = d[r][ev+1]; d[r][eu+1] = u*M1.x + v*M1.z; d[r][ev+1] = u*M1.y + v*M1.w;
            u = d[r][eu+2]; v = d[r][ev+2]; d[r][eu+2] = u*M2.x + v*M2.z; d[r][ev+2] = u*M2.y + v*M2.w;
            u = d[r][eu+3]; v = d[r][ev+3]; d[r][eu+3] = u*M3.x + v*M3.z; d[r][ev+3] = u*M3.y + v*M3.w;
        }
    }

    // ---- stage 9: pairs (q, q+2) for q in {0,1}; p = (q&1)*256 + lane*4 + c ----
    #pragma unroll
    for (int qp = 0; qp < 2; ++qp) {
        int base = 9*512 + qp*256 + lane*4;
        float4 M0 = Wm[base+0], M1 = Wm[base+1], M2 = Wm[base+2], M3 = Wm[base+3];
        #pragma unroll
        for (int r = 0; r < RPW; ++r) {
            int eu = qp*4, ev = (qp+2)*4;
            float u, v;
            u = d[r][eu+0]; v = d[r][ev+0]; d[r][eu+0] = u*M0.x + v*M0.z; d[r][ev+0] = u*M0.y + v*M0.w;
            u = d[r][eu+1]; v = d[r][ev+1]; d[r][eu+1] = u*M1.x + v*M1.z; d[r][ev+1] = u*M1.y + v*M1.w;
            u = d[r][eu+2]; v = d[r][ev+2]; d[r][eu+2] = u*M2.x + v*M2.z; d[r][ev+2] = u*M2.y + v*M2.w;
            u = d[r][eu+3]; v = d[r][ev+3]; d[r][eu+3] = u*M3.x + v*M3.z; d[r][ev+3] = u*M3.y + v*M3.w;
        }
    }

    // ---- store: coalesced float4 ----
    #pragma unroll
    for (int r = 0; r < RPW; ++r) {
        int row = row0 + r;
        if (row < rows) {
            float4* dst = (float4*)(out + (size_t)row * DIM);
            #pragma unroll
            for (int q = 0; q < 4; ++q) {
                float4 v;
                v.x = d[r][q*4+0]; v.y = d[r][q*4+1];
                v.z = d[r][q*4+2]; v.w = d[r][q*4+3];
                dst[q * 64 + lane] = v;
            }
        }
    }
}

extern "C" void kernel_launch(void* const* d_in, const int* in_sizes, int n_in,
                              void* d_out, int out_size, void* d_ws, size_t ws_size,
                              hipStream_t stream) {
    const float* x  = (const float*)d_in[0];
    const float* Ws = (const float*)d_in[1];
    float* out = (float*)d_out;

    int rows = in_sizes[0] / DIM;
    int grid = (rows + ROWS_PER_BLOCK - 1) / ROWS_PER_BLOCK;
    butterfly_kernel<<<grid, 256, 0, stream>>>(x, Ws, out, rows);
}